// Round 3
// baseline (71.297 us; speedup 1.0000x reference)
//
#include <hip/hip_runtime.h>

#define PN 131072
#define PH 1024
#define RPW 32                 // rows per wave
#define NBLK (PN / RPW)        // 4096 one-wave blocks

// SoA packed params, pre-scaled by SC = 2*log2(e):
// pk[0*PH+h] = SC*W1[h,0]
// pk[1*PH+h] = SC*W1[h,1]
// pk[2*PH+h] = SC*b1[h]
// pk[3*PH+h] = w2[h]
// pk[4*PH+h] = w2[h] * (SC*W1[h,1])^2
__global__ __launch_bounds__(256) void prep_kernel(const float* __restrict__ W1,
                                                   const float* __restrict__ b1,
                                                   const float* __restrict__ w2,
                                                   float* __restrict__ pk) {
    int h = blockIdx.x * blockDim.x + threadIdx.x;
    if (h < PH) {
        const float SC = 2.8853900817779268f;  // 2*log2(e)
        float w10 = W1[2 * h], w11 = W1[2 * h + 1], w2h = w2[h];
        float w10s = w10 * SC, w11s = w11 * SC;
        pk[h]          = w10s;
        pk[PH + h]     = w11s;
        pk[2 * PH + h] = b1[h] * SC;
        pk[3 * PH + h] = w2h;
        pk[4 * PH + h] = w2h * w11s * w11s;
    }
}

__global__ __launch_bounds__(64) void pde_kernel(const float* __restrict__ x,
                                                 const float* __restrict__ pk,
                                                 const float* __restrict__ b2p,
                                                 float* __restrict__ out) {
    const int lane = threadIdx.x;          // one wave per block
    const int rbase = blockIdx.x * RPW;    // wave-uniform

    // Load this lane's 16 h-units' params into registers (coalesced, once).
    float w10s[16], w11s[16], b1s[16], w2c[16], c3[16];
    #pragma unroll
    for (int j = 0; j < 16; ++j) {
        const int idx = j * 64 + lane;
        w10s[j] = pk[idx];
        w11s[j] = pk[PH + idx];
        b1s[j]  = pk[2 * PH + idx];
        w2c[j]  = pk[3 * PH + idx];
        c3[j]   = pk[4 * PH + idx];
    }
    const float b2 = b2p[0];

    #pragma unroll 1
    for (int rp = 0; rp < RPW / 2; ++rp) {
        const int row0 = rbase + 2 * rp;   // uniform, even
        // Two rows' x in one uniform 16B load.
        const float4 xp = reinterpret_cast<const float4*>(x)[row0 >> 1];
        const float x0a = xp.x, x1a = xp.y;   // row0
        const float x0b = xp.z, x1b = xp.w;   // row0+1

        float a_out0 = 0.f, a_dt0 = 0.f, a_dx0 = 0.f, a_xx0 = 0.f;
        float a_out1 = 0.f, a_dt1 = 0.f, a_dx1 = 0.f, a_xx1 = 0.f;

        #pragma unroll
        for (int j = 0; j < 16; ++j) {
            const float z0 = __builtin_fmaf(x0a, w10s[j], __builtin_fmaf(x1a, w11s[j], b1s[j]));
            const float z1 = __builtin_fmaf(x0b, w10s[j], __builtin_fmaf(x1b, w11s[j], b1s[j]));
            const float e0 = __builtin_amdgcn_exp2f(z0);
            const float e1 = __builtin_amdgcn_exp2f(z1);
            const float r0 = __builtin_amdgcn_rcpf(e0 + 1.0f);
            const float r1 = __builtin_amdgcn_rcpf(e1 + 1.0f);
            const float t0 = __builtin_fmaf(-2.0f, r0, 1.0f);
            const float t1 = __builtin_fmaf(-2.0f, r1, 1.0f);
            const float q0 = __builtin_fmaf(-t0, t0, 1.0f);
            const float q1 = __builtin_fmaf(-t1, t1, 1.0f);
            const float s0 = q0 * w2c[j];
            const float s1 = q1 * w2c[j];
            const float tq0 = t0 * q0;
            const float tq1 = t1 * q1;
            a_out0 = __builtin_fmaf(t0, w2c[j], a_out0);
            a_out1 = __builtin_fmaf(t1, w2c[j], a_out1);
            a_dt0  = __builtin_fmaf(s0, w10s[j], a_dt0);
            a_dt1  = __builtin_fmaf(s1, w10s[j], a_dt1);
            a_dx0  = __builtin_fmaf(s0, w11s[j], a_dx0);
            a_dx1  = __builtin_fmaf(s1, w11s[j], a_dx1);
            a_xx0  = __builtin_fmaf(tq0, c3[j], a_xx0);
            a_xx1  = __builtin_fmaf(tq1, c3[j], a_xx1);
        }

        // Butterfly reduce all 8 partials across the wave.
        #pragma unroll
        for (int m = 32; m >= 1; m >>= 1) {
            a_out0 += __shfl_xor(a_out0, m, 64);
            a_out1 += __shfl_xor(a_out1, m, 64);
            a_dt0  += __shfl_xor(a_dt0,  m, 64);
            a_dt1  += __shfl_xor(a_dt1,  m, 64);
            a_dx0  += __shfl_xor(a_dx0,  m, 64);
            a_dx1  += __shfl_xor(a_dx1,  m, 64);
            a_xx0  += __shfl_xor(a_xx0,  m, 64);
            a_xx1  += __shfl_xor(a_xx1,  m, 64);
        }

        if (lane == 0) {
            const float invSC  = 0.34657359027997264f;   // 1/SC
            const float invSC2 = 0.12011325347955035f;   // 1/SC^2
            const float o0 = a_out0 + b2;
            const float o1 = a_out1 + b2;
            const float dfdx0 = a_dx0 * invSC;
            const float dfdx1 = a_dx1 * invSC;
            const float pde0 = __builtin_fmaf(0.5f * x1a, x1a, a_dt0 * invSC)
                             - a_xx0 * invSC2
                             + 0.5f * x1a * dfdx0
                             - 0.069444444444444445f * dfdx0 * dfdx0;
            const float pde1 = __builtin_fmaf(0.5f * x1b, x1b, a_dt1 * invSC)
                             - a_xx1 * invSC2
                             + 0.5f * x1b * dfdx1
                             - 0.069444444444444445f * dfdx1 * dfdx1;
            *reinterpret_cast<float2*>(out + row0)      = make_float2(o0, o1);
            *reinterpret_cast<float2*>(out + PN + row0) = make_float2(pde0, pde1);
        }
    }
}

extern "C" void kernel_launch(void* const* d_in, const int* in_sizes, int n_in,
                              void* d_out, int out_size, void* d_ws, size_t ws_size,
                              hipStream_t stream) {
    const float* x  = (const float*)d_in[0];
    const float* W1 = (const float*)d_in[1];
    const float* b1 = (const float*)d_in[2];
    const float* w2 = (const float*)d_in[3];
    const float* b2 = (const float*)d_in[4];
    float* out = (float*)d_out;
    float* pk  = (float*)d_ws;   // 5 * 4 KiB = 20 KiB

    prep_kernel<<<PH / 256, 256, 0, stream>>>(W1, b1, w2, pk);
    pde_kernel<<<NBLK, 64, 0, stream>>>(x, pk, b2, out);
}

// Round 4
// 61.016 us; speedup vs baseline: 1.1685x; 1.1685x over previous
//
#include <hip/hip_runtime.h>

#define PN 131072
#define PH 1024
#define NPAIR (PH / 2)          // 512 h-pairs
#define PPW 128                 // pairs per wave (4 waves cover 512)

typedef _Float16 h2 __attribute__((ext_vector_type(2)));
typedef unsigned short u16x2 __attribute__((ext_vector_type(2)));

static __device__ __forceinline__ h2 splat(float v) {
    _Float16 x = (_Float16)v;
    h2 r = {x, x};
    return r;
}
static __device__ __forceinline__ h2 asf(u16x2 v) { return __builtin_bit_cast(h2, v); }
static __device__ __forceinline__ u16x2 asu(h2 v) { return __builtin_bit_cast(u16x2, v); }

static __device__ __forceinline__ unsigned pack2(float a, float b) {
    h2 v = {(_Float16)a, (_Float16)b};
    return __builtin_bit_cast(unsigned, v);
}

// Layout in d_ws: uint pk[512][8] = 16 KiB, then SW2 (f32) at float index 4096.
// pk[p] = { w10s, w11s, b1s, w2, c1, c2, c3, 0 } as f16x2 pairs for h=2p,2p+1
// w10s = SC*w10 etc (SC = 2*log2 e); c1 = 4*w10*w2; c2 = 4*w11*w2; c3 = 4*w11^2*w2.
__global__ __launch_bounds__(256) void prep_kernel(const float* __restrict__ W1,
                                                   const float* __restrict__ b1,
                                                   const float* __restrict__ w2,
                                                   unsigned* __restrict__ pk,
                                                   float* __restrict__ sw2out) {
    const float SC = 2.8853900817779268f;
    const int t = threadIdx.x;
    float wsum = 0.0f;
    #pragma unroll
    for (int pi = 0; pi < 2; ++pi) {
        const int p = 2 * t + pi;
        const int h0 = 2 * p, h1 = 2 * p + 1;
        const float w10a = W1[2 * h0], w11a = W1[2 * h0 + 1], w2a = w2[h0], b1a = b1[h0];
        const float w10b = W1[2 * h1], w11b = W1[2 * h1 + 1], w2b = w2[h1], b1b = b1[h1];
        unsigned* q = pk + p * 8;
        q[0] = pack2(w10a * SC, w10b * SC);
        q[1] = pack2(w11a * SC, w11b * SC);
        q[2] = pack2(b1a * SC, b1b * SC);
        q[3] = pack2(w2a, w2b);
        q[4] = pack2(4.f * w10a * w2a, 4.f * w10b * w2b);
        q[5] = pack2(4.f * w11a * w2a, 4.f * w11b * w2b);
        q[6] = pack2(4.f * w11a * w11a * w2a, 4.f * w11b * w11b * w2b);
        q[7] = 0u;
        // SW2 accumulated over f16-rounded w2 so A_r's w2 matches exactly.
        wsum += (float)(_Float16)w2a + (float)(_Float16)w2b;
    }
    __shared__ float red[4];
    #pragma unroll
    for (int m = 32; m >= 1; m >>= 1) wsum += __shfl_xor(wsum, m, 64);
    const int wv = t >> 6, ln = t & 63;
    if (ln == 0) red[wv] = wsum;
    __syncthreads();
    if (t == 0) sw2out[0] = red[0] + red[1] + red[2] + red[3];
}

__global__ __launch_bounds__(256, 8) void pde_kernel(const float* __restrict__ x,
                                                     const uint4* __restrict__ pkv,
                                                     const float* __restrict__ sw2p,
                                                     const float* __restrict__ b2p,
                                                     float* __restrict__ out) {
    const int lane = threadIdx.x & 63;
    const int wv   = threadIdx.x >> 6;
    const int wvu  = __builtin_amdgcn_readfirstlane(wv);
    const int row  = blockIdx.x * 64 + lane;

    const float2 xv = reinterpret_cast<const float2*>(x)[row];
    const float x0 = xv.x;
    const float x1 = xv.y;
    const h2 x0h = splat(x0);
    const h2 x1h = splat(x1);

    // Loop-invariant packed constants.
    const h2 MAG = splat(1536.0f);
    const h2 CLO = splat(-11.0f);
    const h2 CHI = splat(11.0f);
    const h2 ONE = splat(1.0f);
    const h2 TWO = splat(2.0f);
    const h2 PC0 = splat(1.0f);
    const h2 PC1 = splat(0.6931472f);
    const h2 PC2 = splat(0.2402265f);
    const h2 PC3 = splat(0.0555041f);
    const u16x2 KU = {(unsigned short)0x7785u, (unsigned short)0x7785u};

    const uint4* __restrict__ pw = pkv + (size_t)wvu * (2 * PPW);

    float Ar = 0.f, Au1 = 0.f, Au2 = 0.f, Au3 = 0.f, Aru = 0.f;

    #pragma unroll 1
    for (int c = 0; c < PPW / 16; ++c) {
        const uint4* __restrict__ pc = pw + 2 * 16 * c;
        h2 aR = splat(0.f), aU1 = splat(0.f), aU2 = splat(0.f), aU3 = splat(0.f), aRU = splat(0.f);
        #pragma unroll
        for (int j = 0; j < 16; ++j) {
            const uint4 A = pc[2 * j];
            const uint4 B = pc[2 * j + 1];
            const h2 w10 = __builtin_bit_cast(h2, A.x);
            const h2 w11 = __builtin_bit_cast(h2, A.y);
            const h2 b1h = __builtin_bit_cast(h2, A.z);
            const h2 w2h = __builtin_bit_cast(h2, A.w);
            const h2 c1h = __builtin_bit_cast(h2, B.x);
            const h2 c2h = __builtin_bit_cast(h2, B.y);
            const h2 c3h = __builtin_bit_cast(h2, B.z);

            h2 zs = x1h * w11 + b1h;
            zs = x0h * w10 + zs;                       // zs = 2*log2e * z
            zs = __builtin_elementwise_max(zs, CLO);
            zs = __builtin_elementwise_min(zs, CHI);

            const h2 m = zs + MAG;                     // round-to-int via magic add
            const h2 k = m - MAG;                      // integer part (exact)
            const h2 f = zs - k;                       // frac in [-0.5, 0.5] (exact)
            h2 p = PC2 + f * PC3;                      // 2^f, deg-3 Horner
            p = PC1 + f * p;
            p = PC0 + f * p;
            const u16x2 kb = asu(m) << 10;             // k<<10 (0x6600 vanishes mod 2^16)
            const h2 e = asf(asu(p) + kb);             // e = 2^zs (exact ldexp via bits)

            const h2 d = e + ONE;
            h2 r = asf(KU - asu(d));                   // rcp bit-trick seed
            r = r * (TWO - d * r);                     // Newton 1
            r = r * (TWO - d * r);                     // Newton 2: r = 1/(1+e^{2z})
            const h2 u = r - r * r;                    // u = r(1-r) = q/4
            const h2 ru = r * u;

            aR  = aR  + r  * w2h;
            aU1 = aU1 + u  * c1h;
            aU2 = aU2 + u  * c2h;
            aU3 = aU3 + u  * c3h;
            aRU = aRU + ru * c3h;
        }
        Ar  += (float)aR.x  + (float)aR.y;
        Au1 += (float)aU1.x + (float)aU1.y;
        Au2 += (float)aU2.x + (float)aU2.y;
        Au3 += (float)aU3.x + (float)aU3.y;
        Aru += (float)aRU.x + (float)aRU.y;
    }

    const float D = Au3 - 2.0f * Aru;    // = sum t*q*w2*w11^2

    __shared__ float4 red[4][64];
    if (wv != 0) {
        red[wv][lane] = make_float4(Ar, Au1, Au2, D);
    }
    __syncthreads();
    if (wv == 0) {
        float sAr = Ar, sAu1 = Au1, sAu2 = Au2, sD = D;
        #pragma unroll
        for (int w = 1; w < 4; ++w) {
            const float4 o = red[w][lane];
            sAr += o.x; sAu1 += o.y; sAu2 += o.z; sD += o.w;
        }
        const float b2  = b2p[0];
        const float SW2 = sw2p[0];
        const float output = SW2 + b2 - 2.0f * sAr;     // sum (1-2r)*w2 + b2
        const float df_dt  = sAu1;
        const float df_dx  = sAu2;
        // pde = 0.5*x1^2 + df_dt + 0.5*df_dxdx + 0.5*x1*df_dx - 0.069444*df_dx^2
        // with df_dxdx = -2*D  ->  0.5*df_dxdx = -D
        const float pde = __builtin_fmaf(0.5f * x1, x1, df_dt)
                        - sD
                        + 0.5f * x1 * df_dx
                        - 0.069444444444444445f * df_dx * df_dx;
        out[row] = output;
        out[PN + row] = pde;
    }
}

extern "C" void kernel_launch(void* const* d_in, const int* in_sizes, int n_in,
                              void* d_out, int out_size, void* d_ws, size_t ws_size,
                              hipStream_t stream) {
    const float* x  = (const float*)d_in[0];
    const float* W1 = (const float*)d_in[1];
    const float* b1 = (const float*)d_in[2];
    const float* w2 = (const float*)d_in[3];
    const float* b2 = (const float*)d_in[4];
    float* out = (float*)d_out;
    unsigned* pk = (unsigned*)d_ws;                  // 512*8*4 = 16 KiB
    float* sw2 = (float*)d_ws + 4096;                // right after pk

    prep_kernel<<<1, 256, 0, stream>>>(W1, b1, w2, pk, sw2);
    pde_kernel<<<PN / 64, 256, 0, stream>>>(x, (const uint4*)pk, sw2, b2, out);
}

// Round 5
// 59.395 us; speedup vs baseline: 1.2004x; 1.0273x over previous
//
#include <hip/hip_runtime.h>

#define PN 131072
#define PH 1024
#define WPB 8               // waves per block
#define HPW (PH / WPB)      // 128 h per wave

// pk[h] = 8 floats: {w10s, w11s, b1s, co, c1, c2, c3, c4}
//  w10s=SC*w10, w11s=SC*w11, b1s=SC*b1 with SC = 2*log2(e)  (so 2^zs = e^{2z})
//  co=-2*w2, c1=4*w10*w2, c2=4*w11*w2, c3=4*w11^2*w2, c4=-8*w11^2*w2
// sw2out[0] = sum of w2 (f32)
__global__ __launch_bounds__(256) void prep_kernel(const float* __restrict__ W1,
                                                   const float* __restrict__ b1,
                                                   const float* __restrict__ w2,
                                                   float* __restrict__ pk,
                                                   float* __restrict__ sw2out) {
    const float SC = 2.8853900817779268f;
    const int t = threadIdx.x;
    float wsum = 0.0f;
    #pragma unroll
    for (int k = 0; k < 4; ++k) {
        const int h = t + k * 256;
        const float w10 = W1[2 * h], w11 = W1[2 * h + 1], w2h = w2[h];
        float* q = pk + (size_t)h * 8;
        q[0] = w10 * SC;
        q[1] = w11 * SC;
        q[2] = b1[h] * SC;
        q[3] = -2.0f * w2h;
        q[4] = 4.0f * w10 * w2h;
        q[5] = 4.0f * w11 * w2h;
        q[6] = 4.0f * w11 * w11 * w2h;
        q[7] = -8.0f * w11 * w11 * w2h;
        wsum += w2h;
    }
    __shared__ float red[4];
    #pragma unroll
    for (int m = 32; m >= 1; m >>= 1) wsum += __shfl_xor(wsum, m, 64);
    const int wv = t >> 6, ln = t & 63;
    if (ln == 0) red[wv] = wsum;
    __syncthreads();
    if (t == 0) sw2out[0] = red[0] + red[1] + red[2] + red[3];
}

__global__ __launch_bounds__(512, 8) void pde_kernel(const float* __restrict__ x,
                                                     const float4* __restrict__ pk4,
                                                     const float* __restrict__ sw2p,
                                                     const float* __restrict__ b2p,
                                                     float* __restrict__ out) {
    const int lane = threadIdx.x & 63;
    const int wv   = threadIdx.x >> 6;                    // 0..7
    const int wvu  = __builtin_amdgcn_readfirstlane(wv);  // keep pk addresses wave-uniform
    const int row  = blockIdx.x * 64 + lane;

    const float2 xv = reinterpret_cast<const float2*>(x)[row];
    const float x0 = xv.x;
    const float x1 = xv.y;

    const float4* __restrict__ pw = pk4 + (size_t)wvu * (2 * HPW);

    float a_r = 0.f, a_u1 = 0.f, a_u2 = 0.f, a_u3 = 0.f, a_u4 = 0.f;

    #pragma unroll 4
    for (int hp = 0; hp < HPW / 2; ++hp) {
        const float4 A0 = pw[4 * hp + 0];   // h even: w10s,w11s,b1s,co
        const float4 A1 = pw[4 * hp + 1];   //         c1,c2,c3,c4
        const float4 B0 = pw[4 * hp + 2];   // h odd
        const float4 B1 = pw[4 * hp + 3];

        float zsa = __builtin_fmaf(x0, A0.x, __builtin_fmaf(x1, A0.y, A0.z));
        float zsb = __builtin_fmaf(x0, B0.x, __builtin_fmaf(x1, B0.y, B0.z));
        zsa = fminf(zsa, 40.0f);
        zsb = fminf(zsb, 40.0f);
        const float ea = __builtin_amdgcn_exp2f(zsa);     // e^{2za} (0 on deep underflow)
        const float eb = __builtin_amdgcn_exp2f(zsb);
        const float da = ea + 1.0f;
        const float db = eb + 1.0f;
        const float rab = __builtin_amdgcn_rcpf(da * db); // shared reciprocal
        const float ra = rab * db;                        // 1/(1+e^{2za}) = sigma(-2za)
        const float rb = rab * da;
        const float ua = __builtin_fmaf(-ra, ra, ra);     // r - r^2
        const float ub = __builtin_fmaf(-rb, rb, rb);
        const float rua = ra * ua;
        const float rub = rb * ub;

        a_r  = __builtin_fmaf(ra,  A0.w, a_r);
        a_r  = __builtin_fmaf(rb,  B0.w, a_r);
        a_u1 = __builtin_fmaf(ua,  A1.x, a_u1);
        a_u1 = __builtin_fmaf(ub,  B1.x, a_u1);
        a_u2 = __builtin_fmaf(ua,  A1.y, a_u2);
        a_u2 = __builtin_fmaf(ub,  B1.y, a_u2);
        a_u3 = __builtin_fmaf(ua,  A1.z, a_u3);
        a_u3 = __builtin_fmaf(ub,  B1.z, a_u3);
        a_u4 = __builtin_fmaf(rua, A1.w, a_u4);
        a_u4 = __builtin_fmaf(rub, B1.w, a_u4);
    }

    const float aD = a_u3 + a_u4;   // = sum t*q*w2*w11^2 over this wave's h-chunk

    __shared__ float4 red[WPB][64];
    if (wv != 0) {
        red[wv][lane] = make_float4(a_r, a_u1, a_u2, aD);
    }
    __syncthreads();
    if (wv == 0) {
        float s_r = a_r, s_u1 = a_u1, s_u2 = a_u2, sD = aD;
        #pragma unroll
        for (int w = 1; w < WPB; ++w) {
            const float4 o = red[w][lane];
            s_r += o.x; s_u1 += o.y; s_u2 += o.z; sD += o.w;
        }
        const float b2  = b2p[0];
        const float SW2 = sw2p[0];
        const float output = SW2 + b2 + s_r;              // sum t*w2 + b2
        const float df_dt  = s_u1;
        const float df_dx  = s_u2;
        // pde = 0.5*x1^2 + df_dt + 0.5*df_dxdx + 0.5*x1*df_dx - c^2/(4 c_f) df_dx^2
        // 0.5*df_dxdx = -sD
        const float pde = __builtin_fmaf(0.5f * x1, x1, df_dt)
                        - sD
                        + 0.5f * x1 * df_dx
                        - 0.069444444444444445f * df_dx * df_dx;
        out[row] = output;
        out[PN + row] = pde;
    }
}

extern "C" void kernel_launch(void* const* d_in, const int* in_sizes, int n_in,
                              void* d_out, int out_size, void* d_ws, size_t ws_size,
                              hipStream_t stream) {
    const float* x  = (const float*)d_in[0];
    const float* W1 = (const float*)d_in[1];
    const float* b1 = (const float*)d_in[2];
    const float* w2 = (const float*)d_in[3];
    const float* b2 = (const float*)d_in[4];
    float* out = (float*)d_out;
    float* pk  = (float*)d_ws;                 // 1024 * 32 B = 32 KiB
    float* sw2 = (float*)d_ws + 8192;          // after pk

    prep_kernel<<<1, 256, 0, stream>>>(W1, b1, w2, pk, sw2);
    pde_kernel<<<PN / 64, 512, 0, stream>>>(x, (const float4*)pk, sw2, b2, out);
}